// Round 6
// baseline (564.637 us; speedup 1.0000x reference)
//
#include <hip/hip_runtime.h>
#include <hip/hip_bf16.h>

// ---------------------------------------------------------------------------
// 4-layer GCN forward (PyG gcn_norm: add self-loops, D^-1/2 A D^-1/2)
// Reassociated: h' = relu((A·h)·W + b)  [A·(hW) == (A·h)·W exactly]
// ALL 4 layers fused: per block of 16 nodes:
//   phase 1: gather/aggregate 16 node rows into LDS (16 thr/node, float4,
//            depth-2 software-pipelined edge loop: loads for edge j+2 in
//            flight while accumulating edge j)
//   phase 2: 16x128 @ 128xFOUT register GEMM, W read from L2, bias(+relu)
// 100% occupancy target: VGPR<=64, LDS 8.4KB, launch_bounds(256,8).
// ---------------------------------------------------------------------------

#define F_DIM 128

#define SCAN_T 256
#define SCAN_I 8
#define SCAN_CHUNK (SCAN_T * SCAN_I)   // 2048 items per block

__global__ void count_dst_kernel(const int* __restrict__ dst, int* __restrict__ count, int E) {
    int e = blockIdx.x * blockDim.x + threadIdx.x;
    if (e < E) atomicAdd(&count[dst[e]], 1);
}

__global__ void dinv_kernel(const int* __restrict__ count, float* __restrict__ dinv, int n) {
    int i = blockIdx.x * blockDim.x + threadIdx.x;
    if (i < n) dinv[i] = rsqrtf((float)(count[i] + 1));  // +1 self-loop, always > 0
}

// ---- two-level scan of (count[i]+1) ---------------------------------------
__global__ __launch_bounds__(SCAN_T) void scan_partial_kernel(const int* __restrict__ count,
                                                              int* __restrict__ blocksum, int n) {
    int b = blockIdx.x, t = threadIdx.x;
    int base = b * SCAN_CHUNK + t * SCAN_I;
    int s = 0;
#pragma unroll
    for (int j = 0; j < SCAN_I; ++j) {
        int i = base + j;
        if (i < n) s += count[i] + 1;
    }
    __shared__ int red[SCAN_T];
    red[t] = s;
    __syncthreads();
    for (int off = SCAN_T / 2; off > 0; off >>= 1) {
        if (t < off) red[t] += red[t + off];
        __syncthreads();
    }
    if (t == 0) blocksum[b] = red[0];
}

__global__ __launch_bounds__(1024) void scan_sums_kernel(const int* __restrict__ blocksum,
                                                         int* __restrict__ blockoff, int nb) {
    __shared__ int sums[1024];
    int t = threadIdx.x;
    sums[t] = (t < nb) ? blocksum[t] : 0;
    __syncthreads();
    for (int off = 1; off < 1024; off <<= 1) {
        int v = (t >= off) ? sums[t - off] : 0;
        __syncthreads();
        sums[t] += v;
        __syncthreads();
    }
    if (t < nb) blockoff[t] = (t == 0) ? 0 : sums[t - 1];
    if (t == 0) blockoff[nb] = sums[nb - 1];
}

__global__ __launch_bounds__(SCAN_T) void scan_write_kernel(const int* __restrict__ count,
                                                            const int* __restrict__ blockoff,
                                                            int* __restrict__ rowptr,
                                                            int* __restrict__ writepos,
                                                            int n, int nb) {
    int b = blockIdx.x, t = threadIdx.x;
    int base = b * SCAN_CHUNK + t * SCAN_I;
    int c[SCAN_I];
    int s = 0;
#pragma unroll
    for (int j = 0; j < SCAN_I; ++j) {
        int i = base + j;
        c[j] = (i < n) ? count[i] + 1 : 0;
        s += c[j];
    }
    __shared__ int sums[SCAN_T];
    sums[t] = s;
    __syncthreads();
    for (int off = 1; off < SCAN_T; off <<= 1) {
        int v = (t >= off) ? sums[t - off] : 0;
        __syncthreads();
        sums[t] += v;
        __syncthreads();
    }
    int offset = blockoff[b] + ((t == 0) ? 0 : sums[t - 1]);
#pragma unroll
    for (int j = 0; j < SCAN_I; ++j) {
        int i = base + j;
        if (i < n) {
            rowptr[i] = offset;
            writepos[i] = offset;
            offset += c[j];
        }
    }
    if (b == 0 && t == 0) rowptr[n] = blockoff[nb];
}

// ---- CSR fill -------------------------------------------------------------
__global__ void fill_self_kernel(int* __restrict__ writepos, int* __restrict__ col,
                                 float* __restrict__ val, const float* __restrict__ dinv, int n) {
    int i = blockIdx.x * blockDim.x + threadIdx.x;
    if (i < n) {
        int p = atomicAdd(&writepos[i], 1);
        col[p] = i;
        val[p] = dinv[i] * dinv[i];
    }
}

__global__ void fill_edges_kernel(const int* __restrict__ src, const int* __restrict__ dst,
                                  int* __restrict__ writepos, int* __restrict__ col,
                                  float* __restrict__ val, const float* __restrict__ dinv, int E) {
    int e = blockIdx.x * blockDim.x + threadIdx.x;
    if (e < E) {
        int s = src[e], d = dst[e];
        int p = atomicAdd(&writepos[d], 1);
        col[p] = s;
        val[p] = dinv[s] * dinv[d];
    }
}

// ---- fused layer: out[16 nodes] = act( (A·Hin)[16x128] @ W[128xFOUT] + b )
// FOUT4: output float4s per row (32 -> 128 feats, 10 -> 40 feats)
// block = 256 threads, BM = 16 nodes/block, 16 threads per node
template <int FOUT4, int RELU>
__global__ __launch_bounds__(256, 8) void fused_layer_kernel(const int* __restrict__ rowptr,
                                                             const int* __restrict__ col,
                                                             const float* __restrict__ val,
                                                             const float* __restrict__ Hin,
                                                             const float* __restrict__ W,
                                                             const float* __restrict__ bias,
                                                             float* __restrict__ Hout,
                                                             int n) {
    // row stride 132 floats: float4-aligned; phase-2 reads are 2-address
    // broadcasts (conflict-free).
    __shared__ float agg[16][132];

    const float4* H4 = (const float4*)Hin;
    const float4* W4 = (const float4*)W;

    // ---- phase 1: aggregate 16 rows into LDS, 16 threads per node ----
    // Lane p owns float4 indices {p, p+16}: one wave instr per q reads
    // 16 consecutive float4s = 256B fully-contiguous per row.
    {
        int m = threadIdx.x >> 4;        // node in tile 0..15
        int p = threadIdx.x & 15;        // lane in group
        int node = blockIdx.x * 16 + m;
        float4 acc0 = make_float4(0.f, 0.f, 0.f, 0.f);
        float4 acc1 = make_float4(0.f, 0.f, 0.f, 0.f);
        if (node < n) {
            int s = rowptr[node], e = rowptr[node + 1];
            // depth-2 software pipeline over edges: stages A (even) / B (odd)
            int jA = s, jB = s + 1;
            float vA = 0.f, vB = 0.f;
            float4 hA0, hA1, hB0, hB1;
            if (jA < e) {
                int c = col[jA]; vA = val[jA];
                const float4* hp = H4 + (size_t)c * 32 + p;
                hA0 = hp[0]; hA1 = hp[16];
            }
            if (jB < e) {
                int c = col[jB]; vB = val[jB];
                const float4* hp = H4 + (size_t)c * 32 + p;
                hB0 = hp[0]; hB1 = hp[16];
            }
            while (jA < e) {
                // consume stage A (edge jA), then refill A with edge jA+2
                acc0.x += vA * hA0.x; acc0.y += vA * hA0.y;
                acc0.z += vA * hA0.z; acc0.w += vA * hA0.w;
                acc1.x += vA * hA1.x; acc1.y += vA * hA1.y;
                acc1.z += vA * hA1.z; acc1.w += vA * hA1.w;
                int jn = jA + 2;
                if (jn < e) {
                    int c = col[jn]; vA = val[jn];
                    const float4* hp = H4 + (size_t)c * 32 + p;
                    hA0 = hp[0]; hA1 = hp[16];
                }
                jA = jn;
                if (jB < e) {
                    acc0.x += vB * hB0.x; acc0.y += vB * hB0.y;
                    acc0.z += vB * hB0.z; acc0.w += vB * hB0.w;
                    acc1.x += vB * hB1.x; acc1.y += vB * hB1.y;
                    acc1.z += vB * hB1.z; acc1.w += vB * hB1.w;
                    jn = jB + 2;
                    if (jn < e) {
                        int c = col[jn]; vB = val[jn];
                        const float4* hp = H4 + (size_t)c * 32 + p;
                        hB0 = hp[0]; hB1 = hp[16];
                    }
                    jB = jn;
                }
            }
        }
        *(float4*)&agg[m][p * 4] = acc0;
        *(float4*)&agg[m][(p + 16) * 4] = acc1;
    }
    __syncthreads();

    // ---- phase 2: agg[16][128] @ W[128][FOUT] from L2, register GEMM ----
    constexpr int TXM = (FOUT4 > 16) ? 32 : 16;  // feat4 lanes
    constexpr int NG = 256 / TXM;                // row groups
    constexpr int ROWS = 16 / NG;                // rows per thread
    int tx = threadIdx.x & (TXM - 1);
    int ty = threadIdx.x / TXM;

    float4 oacc[ROWS];
#pragma unroll
    for (int i = 0; i < ROWS; ++i) oacc[i] = make_float4(0.f, 0.f, 0.f, 0.f);

    if (tx < FOUT4) {
#pragma unroll 4
        for (int k = 0; k < 128; ++k) {
            float4 b = W4[(size_t)k * FOUT4 + tx];
#pragma unroll
            for (int i = 0; i < ROWS; ++i) {
                float a = agg[i * NG + ty][k];
                oacc[i].x += a * b.x;
                oacc[i].y += a * b.y;
                oacc[i].z += a * b.z;
                oacc[i].w += a * b.w;
            }
        }

        float4 bv = ((const float4*)bias)[tx];
#pragma unroll
        for (int i = 0; i < ROWS; ++i) {
            int node = blockIdx.x * 16 + i * NG + ty;
            if (node < n) {
                float4 o;
                o.x = oacc[i].x + bv.x;
                o.y = oacc[i].y + bv.y;
                o.z = oacc[i].z + bv.z;
                o.w = oacc[i].w + bv.w;
                if (RELU) {
                    o.x = fmaxf(o.x, 0.f);
                    o.y = fmaxf(o.y, 0.f);
                    o.z = fmaxf(o.z, 0.f);
                    o.w = fmaxf(o.w, 0.f);
                }
                ((float4*)Hout)[(size_t)node * FOUT4 + tx] = o;
            }
        }
    }
}

extern "C" void kernel_launch(void* const* d_in, const int* in_sizes, int n_in,
                              void* d_out, int out_size, void* d_ws, size_t ws_size,
                              hipStream_t stream) {
    const float* x = (const float*)d_in[0];
    const int* edge_index = (const int*)d_in[1];
    const float* W0 = (const float*)d_in[2];
    const float* b0 = (const float*)d_in[3];
    const float* W1 = (const float*)d_in[4];
    const float* b1 = (const float*)d_in[5];
    const float* W2 = (const float*)d_in[6];
    const float* b2 = (const float*)d_in[7];
    const float* W3 = (const float*)d_in[8];
    const float* b3 = (const float*)d_in[9];

    const int E = in_sizes[1] / 2;
    const int N = in_sizes[0] / F_DIM;
    const int NNZ = E + N;
    const int NB = (N + SCAN_CHUNK - 1) / SCAN_CHUNK;

    const int* src = edge_index;
    const int* dst = edge_index + E;

    char* ws = (char*)d_ws;
    size_t off = 0;
    auto carve = [&](size_t bytes) -> void* {
        void* p = ws + off;
        off = (off + bytes + 255) & ~(size_t)255;
        return p;
    };
    float* bufA = (float*)carve((size_t)N * F_DIM * sizeof(float));
    float* bufB = (float*)carve((size_t)N * F_DIM * sizeof(float));
    int* count = (int*)carve((size_t)N * sizeof(int));
    float* dinv = (float*)carve((size_t)N * sizeof(float));
    int* rowptr = (int*)carve((size_t)(N + 1) * sizeof(int));
    int* writepos = (int*)carve((size_t)N * sizeof(int));
    int* colbuf = (int*)carve((size_t)NNZ * sizeof(int));
    float* valbuf = (float*)carve((size_t)NNZ * sizeof(float));
    int* blocksum = (int*)carve((size_t)NB * sizeof(int));
    int* blockoff = (int*)carve((size_t)(NB + 1) * sizeof(int));
    (void)ws_size;

    // preprocessing: degree -> dinv -> scan -> CSR fill
    hipMemsetAsync(count, 0, (size_t)N * sizeof(int), stream);
    count_dst_kernel<<<(E + 255) / 256, 256, 0, stream>>>(dst, count, E);
    dinv_kernel<<<(N + 255) / 256, 256, 0, stream>>>(count, dinv, N);
    scan_partial_kernel<<<NB, SCAN_T, 0, stream>>>(count, blocksum, N);
    scan_sums_kernel<<<1, 1024, 0, stream>>>(blocksum, blockoff, NB);
    scan_write_kernel<<<NB, SCAN_T, 0, stream>>>(count, blockoff, rowptr, writepos, N, NB);
    fill_self_kernel<<<(N + 255) / 256, 256, 0, stream>>>(writepos, colbuf, valbuf, dinv, N);
    fill_edges_kernel<<<(E + 255) / 256, 256, 0, stream>>>(src, dst, writepos, colbuf, valbuf, dinv, E);

    // 4 fused layers
    int nblk = (N + 15) / 16;
    fused_layer_kernel<32, 1><<<nblk, 256, 0, stream>>>(rowptr, colbuf, valbuf, x, W0, b0, bufB, N);
    fused_layer_kernel<32, 1><<<nblk, 256, 0, stream>>>(rowptr, colbuf, valbuf, bufB, W1, b1, bufA, N);
    fused_layer_kernel<32, 1><<<nblk, 256, 0, stream>>>(rowptr, colbuf, valbuf, bufA, W2, b2, bufB, N);
    fused_layer_kernel<10, 0><<<nblk, 256, 0, stream>>>(rowptr, colbuf, valbuf, bufB, W3, b3, (float*)d_out, N);
}

// Round 7
// 414.586 us; speedup vs baseline: 1.3619x; 1.3619x over previous
//
#include <hip/hip_runtime.h>
#include <hip/hip_bf16.h>

// ---------------------------------------------------------------------------
// 4-layer GCN forward (PyG gcn_norm: add self-loops, D^-1/2 A D^-1/2)
// Hidden layers (reassociated): h' = relu((A·h)·W + b), fused gather+GEMM
//   (R4 structure: 32 nodes/block, 8 thr/node, interleaved float4, unroll x2)
// Last layer (direct order): hw3 = h@W3 (dense GEMM, 16MB out), then
//   out = A·hw3 + b3  -- gather footprint 16MB => L2-resident.
// ---------------------------------------------------------------------------

#define F_DIM 128

#define SCAN_T 256
#define SCAN_I 8
#define SCAN_CHUNK (SCAN_T * SCAN_I)   // 2048 items per block

__global__ void count_dst_kernel(const int* __restrict__ dst, int* __restrict__ count, int E) {
    int e = blockIdx.x * blockDim.x + threadIdx.x;
    if (e < E) atomicAdd(&count[dst[e]], 1);
}

__global__ void dinv_kernel(const int* __restrict__ count, float* __restrict__ dinv, int n) {
    int i = blockIdx.x * blockDim.x + threadIdx.x;
    if (i < n) dinv[i] = rsqrtf((float)(count[i] + 1));  // +1 self-loop, always > 0
}

// ---- two-level scan of (count[i]+1) ---------------------------------------
__global__ __launch_bounds__(SCAN_T) void scan_partial_kernel(const int* __restrict__ count,
                                                              int* __restrict__ blocksum, int n) {
    int b = blockIdx.x, t = threadIdx.x;
    int base = b * SCAN_CHUNK + t * SCAN_I;
    int s = 0;
#pragma unroll
    for (int j = 0; j < SCAN_I; ++j) {
        int i = base + j;
        if (i < n) s += count[i] + 1;
    }
    __shared__ int red[SCAN_T];
    red[t] = s;
    __syncthreads();
    for (int off = SCAN_T / 2; off > 0; off >>= 1) {
        if (t < off) red[t] += red[t + off];
        __syncthreads();
    }
    if (t == 0) blocksum[b] = red[0];
}

__global__ __launch_bounds__(1024) void scan_sums_kernel(const int* __restrict__ blocksum,
                                                         int* __restrict__ blockoff, int nb) {
    __shared__ int sums[1024];
    int t = threadIdx.x;
    sums[t] = (t < nb) ? blocksum[t] : 0;
    __syncthreads();
    for (int off = 1; off < 1024; off <<= 1) {
        int v = (t >= off) ? sums[t - off] : 0;
        __syncthreads();
        sums[t] += v;
        __syncthreads();
    }
    if (t < nb) blockoff[t] = (t == 0) ? 0 : sums[t - 1];
    if (t == 0) blockoff[nb] = sums[nb - 1];
}

__global__ __launch_bounds__(SCAN_T) void scan_write_kernel(const int* __restrict__ count,
                                                            const int* __restrict__ blockoff,
                                                            int* __restrict__ rowptr,
                                                            int* __restrict__ writepos,
                                                            int n, int nb) {
    int b = blockIdx.x, t = threadIdx.x;
    int base = b * SCAN_CHUNK + t * SCAN_I;
    int c[SCAN_I];
    int s = 0;
#pragma unroll
    for (int j = 0; j < SCAN_I; ++j) {
        int i = base + j;
        c[j] = (i < n) ? count[i] + 1 : 0;
        s += c[j];
    }
    __shared__ int sums[SCAN_T];
    sums[t] = s;
    __syncthreads();
    for (int off = 1; off < SCAN_T; off <<= 1) {
        int v = (t >= off) ? sums[t - off] : 0;
        __syncthreads();
        sums[t] += v;
        __syncthreads();
    }
    int offset = blockoff[b] + ((t == 0) ? 0 : sums[t - 1]);
#pragma unroll
    for (int j = 0; j < SCAN_I; ++j) {
        int i = base + j;
        if (i < n) {
            rowptr[i] = offset;
            writepos[i] = offset;
            offset += c[j];
        }
    }
    if (b == 0 && t == 0) rowptr[n] = blockoff[nb];
}

// ---- CSR fill -------------------------------------------------------------
__global__ void fill_self_kernel(int* __restrict__ writepos, int* __restrict__ col,
                                 float* __restrict__ val, const float* __restrict__ dinv, int n) {
    int i = blockIdx.x * blockDim.x + threadIdx.x;
    if (i < n) {
        int p = atomicAdd(&writepos[i], 1);
        col[p] = i;
        val[p] = dinv[i] * dinv[i];
    }
}

__global__ void fill_edges_kernel(const int* __restrict__ src, const int* __restrict__ dst,
                                  int* __restrict__ writepos, int* __restrict__ col,
                                  float* __restrict__ val, const float* __restrict__ dinv, int E) {
    int e = blockIdx.x * blockDim.x + threadIdx.x;
    if (e < E) {
        int s = src[e], d = dst[e];
        int p = atomicAdd(&writepos[d], 1);
        col[p] = s;
        val[p] = dinv[s] * dinv[d];
    }
}

// ---- fused hidden layer: out[32 nodes] = relu( (A·Hin)[32x128] @ W + b ) --
// block = 256 threads, BM = 32 nodes/block, 8 threads/node (R4 structure)
template <int FOUT4, int RELU>
__global__ __launch_bounds__(256, 6) void fused_layer_kernel(const int* __restrict__ rowptr,
                                                             const int* __restrict__ col,
                                                             const float* __restrict__ val,
                                                             const float* __restrict__ Hin,
                                                             const float* __restrict__ W,
                                                             const float* __restrict__ bias,
                                                             float* __restrict__ Hout,
                                                             int n) {
    __shared__ float agg[32][132];

    const float4* H4 = (const float4*)Hin;
    const float4* W4 = (const float4*)W;

    // ---- phase 1: aggregate 32 rows into LDS, 8 threads per node ----
    // Thread p owns float4 indices {p, p+8, p+16, p+24}: contiguous 128B
    // per wave instruction.
    {
        int m = threadIdx.x >> 3;
        int p = threadIdx.x & 7;
        int node = blockIdx.x * 32 + m;
        float4 acc[4];
#pragma unroll
        for (int q = 0; q < 4; ++q) acc[q] = make_float4(0.f, 0.f, 0.f, 0.f);
        if (node < n) {
            int s = rowptr[node], e = rowptr[node + 1];
            int j = s;
            for (; j + 1 < e; j += 2) {
                int c0 = col[j], c1 = col[j + 1];
                float v0 = val[j], v1 = val[j + 1];
                const float4* hp0 = H4 + (size_t)c0 * 32 + p;
                const float4* hp1 = H4 + (size_t)c1 * 32 + p;
                float4 h0[4], h1[4];
#pragma unroll
                for (int q = 0; q < 4; ++q) h0[q] = hp0[q * 8];
#pragma unroll
                for (int q = 0; q < 4; ++q) h1[q] = hp1[q * 8];
#pragma unroll
                for (int q = 0; q < 4; ++q) {
                    acc[q].x += v0 * h0[q].x + v1 * h1[q].x;
                    acc[q].y += v0 * h0[q].y + v1 * h1[q].y;
                    acc[q].z += v0 * h0[q].z + v1 * h1[q].z;
                    acc[q].w += v0 * h0[q].w + v1 * h1[q].w;
                }
            }
            if (j < e) {
                int c0 = col[j];
                float v0 = val[j];
                const float4* hp0 = H4 + (size_t)c0 * 32 + p;
#pragma unroll
                for (int q = 0; q < 4; ++q) {
                    float4 h = hp0[q * 8];
                    acc[q].x += v0 * h.x;
                    acc[q].y += v0 * h.y;
                    acc[q].z += v0 * h.z;
                    acc[q].w += v0 * h.w;
                }
            }
        }
#pragma unroll
        for (int q = 0; q < 4; ++q)
            *(float4*)&agg[m][(p + 8 * q) * 4] = acc[q];
    }
    __syncthreads();

    // ---- phase 2: agg[32][128] @ W[128][FOUT] from L2, register GEMM ----
    constexpr int TXM = 32;
    constexpr int NG = 256 / TXM;      // 8 row groups
    constexpr int ROWS = 32 / NG;      // 4 rows per thread
    int tx = threadIdx.x & (TXM - 1);
    int ty = threadIdx.x / TXM;

    float4 oacc[ROWS];
#pragma unroll
    for (int i = 0; i < ROWS; ++i) oacc[i] = make_float4(0.f, 0.f, 0.f, 0.f);

#pragma unroll 4
    for (int k = 0; k < 128; ++k) {
        float4 b = W4[(size_t)k * FOUT4 + tx];
#pragma unroll
        for (int i = 0; i < ROWS; ++i) {
            float a = agg[i * NG + ty][k];
            oacc[i].x += a * b.x;
            oacc[i].y += a * b.y;
            oacc[i].z += a * b.z;
            oacc[i].w += a * b.w;
        }
    }

    float4 bv = ((const float4*)bias)[tx];
#pragma unroll
    for (int i = 0; i < ROWS; ++i) {
        int node = blockIdx.x * 32 + i * NG + ty;
        if (node < n) {
            float4 o;
            o.x = oacc[i].x + bv.x;
            o.y = oacc[i].y + bv.y;
            o.z = oacc[i].z + bv.z;
            o.w = oacc[i].w + bv.w;
            if (RELU) {
                o.x = fmaxf(o.x, 0.f);
                o.y = fmaxf(o.y, 0.f);
                o.z = fmaxf(o.z, 0.f);
                o.w = fmaxf(o.w, 0.f);
            }
            ((float4*)Hout)[(size_t)node * FOUT4 + tx] = o;
        }
    }
}

// ---- gemm40: out[N][40] = H[N][128] @ W[128][40] (NO bias) ----------------
// block 256 threads = 64 nodes x 4 feat-groups of 10
__global__ __launch_bounds__(256) void gemm40_kernel(const float* __restrict__ H,
                                                     const float* __restrict__ W,
                                                     float* __restrict__ out, int n) {
    __shared__ float hs[64][129];   // stride 129: (m+k)%32 banks -> 2-way max
    __shared__ float ws[128][40];   // 20KB, wave-uniform reads (broadcast)

    int t = threadIdx.x;
    int rowBase = blockIdx.x * 64;

    // stage W (5120 floats, 20 per thread)
    for (int i = t; i < 128 * 40; i += 256) ((float*)ws)[0 * 0 + i] = W[i];
    // note: ws is [128][40] contiguous; linear fill is fine
    // stage H tile: 2048 float4, 8 per thread, coalesced
    {
        const float4* H4 = (const float4*)H;
#pragma unroll
        for (int i = 0; i < 8; ++i) {
            int f = t + 256 * i;           // float4 index in tile
            int m = f >> 5, c4 = f & 31;
            int node = rowBase + m;
            float4 v = make_float4(0.f, 0.f, 0.f, 0.f);
            if (node < n) v = H4[(size_t)node * 32 + c4];
            hs[m][c4 * 4 + 0] = v.x;
            hs[m][c4 * 4 + 1] = v.y;
            hs[m][c4 * 4 + 2] = v.z;
            hs[m][c4 * 4 + 3] = v.w;
        }
    }
    __syncthreads();

    int m = t & 63;        // node in tile
    int g = t >> 6;        // feat group (10 feats)
    float acc[10];
#pragma unroll
    for (int j = 0; j < 10; ++j) acc[j] = 0.f;

    for (int k = 0; k < 128; ++k) {
        float a = hs[m][k];
        const float* wrow = &ws[k][g * 10];
#pragma unroll
        for (int j = 0; j < 10; ++j) acc[j] += a * wrow[j];
    }

    int node = rowBase + m;
    if (node < n) {
        float* op = out + (size_t)node * 40 + g * 10;
#pragma unroll
        for (int j = 0; j < 10; ++j) op[j] = acc[j];
    }
}

// ---- gather40: out[dst] = sum val * hw3[src] + b3, 40 feats ---------------
// block 256, 32 nodes/block, 8 threads/node
__global__ __launch_bounds__(256, 8) void gather40_kernel(const int* __restrict__ rowptr,
                                                          const int* __restrict__ col,
                                                          const float* __restrict__ val,
                                                          const float* __restrict__ hw3,
                                                          const float* __restrict__ bias,
                                                          float* __restrict__ out, int n) {
    int m = threadIdx.x >> 3;
    int p = threadIdx.x & 7;
    int node = blockIdx.x * 32 + m;
    if (node >= n) return;

    float4 acc0 = make_float4(0.f, 0.f, 0.f, 0.f);
    float4 acc1 = make_float4(0.f, 0.f, 0.f, 0.f);   // only p<2 uses

    int s = rowptr[node], e = rowptr[node + 1];
    int j = s;
    for (; j + 1 < e; j += 2) {
        int c0 = col[j], c1 = col[j + 1];
        float v0 = val[j], v1 = val[j + 1];
        const float4* r0 = (const float4*)(hw3 + (size_t)c0 * 40);
        const float4* r1 = (const float4*)(hw3 + (size_t)c1 * 40);
        float4 a0 = r0[p], a1 = r1[p];
        acc0.x += v0 * a0.x + v1 * a1.x;
        acc0.y += v0 * a0.y + v1 * a1.y;
        acc0.z += v0 * a0.z + v1 * a1.z;
        acc0.w += v0 * a0.w + v1 * a1.w;
        if (p < 2) {
            float4 b0 = r0[8 + p], b1 = r1[8 + p];
            acc1.x += v0 * b0.x + v1 * b1.x;
            acc1.y += v0 * b0.y + v1 * b1.y;
            acc1.z += v0 * b0.z + v1 * b1.z;
            acc1.w += v0 * b0.w + v1 * b1.w;
        }
    }
    if (j < e) {
        int c0 = col[j];
        float v0 = val[j];
        const float4* r0 = (const float4*)(hw3 + (size_t)c0 * 40);
        float4 a0 = r0[p];
        acc0.x += v0 * a0.x;
        acc0.y += v0 * a0.y;
        acc0.z += v0 * a0.z;
        acc0.w += v0 * a0.w;
        if (p < 2) {
            float4 b0 = r0[8 + p];
            acc1.x += v0 * b0.x;
            acc1.y += v0 * b0.y;
            acc1.z += v0 * b0.z;
            acc1.w += v0 * b0.w;
        }
    }

    const float4* bi = (const float4*)bias;
    float4 bv = bi[p];
    float4 o0;
    o0.x = acc0.x + bv.x; o0.y = acc0.y + bv.y;
    o0.z = acc0.z + bv.z; o0.w = acc0.w + bv.w;
    ((float4*)(out + (size_t)node * 40))[p] = o0;
    if (p < 2) {
        float4 bw = bi[8 + p];
        float4 o1;
        o1.x = acc1.x + bw.x; o1.y = acc1.y + bw.y;
        o1.z = acc1.z + bw.z; o1.w = acc1.w + bw.w;
        ((float4*)(out + (size_t)node * 40))[8 + p] = o1;
    }
}

extern "C" void kernel_launch(void* const* d_in, const int* in_sizes, int n_in,
                              void* d_out, int out_size, void* d_ws, size_t ws_size,
                              hipStream_t stream) {
    const float* x = (const float*)d_in[0];
    const int* edge_index = (const int*)d_in[1];
    const float* W0 = (const float*)d_in[2];
    const float* b0 = (const float*)d_in[3];
    const float* W1 = (const float*)d_in[4];
    const float* b1 = (const float*)d_in[5];
    const float* W2 = (const float*)d_in[6];
    const float* b2 = (const float*)d_in[7];
    const float* W3 = (const float*)d_in[8];
    const float* b3 = (const float*)d_in[9];

    const int E = in_sizes[1] / 2;
    const int N = in_sizes[0] / F_DIM;
    const int NNZ = E + N;
    const int NB = (N + SCAN_CHUNK - 1) / SCAN_CHUNK;

    const int* src = edge_index;
    const int* dst = edge_index + E;

    char* ws = (char*)d_ws;
    size_t off = 0;
    auto carve = [&](size_t bytes) -> void* {
        void* p = ws + off;
        off = (off + bytes + 255) & ~(size_t)255;
        return p;
    };
    float* bufA = (float*)carve((size_t)N * F_DIM * sizeof(float));
    float* bufB = (float*)carve((size_t)N * F_DIM * sizeof(float));
    int* count = (int*)carve((size_t)N * sizeof(int));
    float* dinv = (float*)carve((size_t)N * sizeof(float));
    int* rowptr = (int*)carve((size_t)(N + 1) * sizeof(int));
    int* writepos = (int*)carve((size_t)N * sizeof(int));
    int* colbuf = (int*)carve((size_t)NNZ * sizeof(int));
    float* valbuf = (float*)carve((size_t)NNZ * sizeof(float));
    int* blocksum = (int*)carve((size_t)NB * sizeof(int));
    int* blockoff = (int*)carve((size_t)(NB + 1) * sizeof(int));
    (void)ws_size;

    // preprocessing: degree -> dinv -> scan -> CSR fill
    hipMemsetAsync(count, 0, (size_t)N * sizeof(int), stream);
    count_dst_kernel<<<(E + 255) / 256, 256, 0, stream>>>(dst, count, E);
    dinv_kernel<<<(N + 255) / 256, 256, 0, stream>>>(count, dinv, N);
    scan_partial_kernel<<<NB, SCAN_T, 0, stream>>>(count, blocksum, N);
    scan_sums_kernel<<<1, 1024, 0, stream>>>(blocksum, blockoff, NB);
    scan_write_kernel<<<NB, SCAN_T, 0, stream>>>(count, blockoff, rowptr, writepos, N, NB);
    fill_self_kernel<<<(N + 255) / 256, 256, 0, stream>>>(writepos, colbuf, valbuf, dinv, N);
    fill_edges_kernel<<<(E + 255) / 256, 256, 0, stream>>>(src, dst, writepos, colbuf, valbuf, dinv, E);

    // 3 fused hidden layers
    int nblk32 = (N + 31) / 32;
    fused_layer_kernel<32, 1><<<nblk32, 256, 0, stream>>>(rowptr, colbuf, valbuf, x, W0, b0, bufB, N);
    fused_layer_kernel<32, 1><<<nblk32, 256, 0, stream>>>(rowptr, colbuf, valbuf, bufB, W1, b1, bufA, N);
    fused_layer_kernel<32, 1><<<nblk32, 256, 0, stream>>>(rowptr, colbuf, valbuf, bufA, W2, b2, bufB, N);

    // last layer: hw3 = h @ W3 (dense), then out = A·hw3 + b3 (L2-resident gather)
    gemm40_kernel<<<(N + 63) / 64, 256, 0, stream>>>(bufB, W3, bufA, N);
    gather40_kernel<<<nblk32, 256, 0, stream>>>(rowptr, colbuf, valbuf, bufA, b3, (float*)d_out, N);
}

// Round 8
// 368.471 us; speedup vs baseline: 1.5324x; 1.1252x over previous
//
#include <hip/hip_runtime.h>
#include <hip/hip_bf16.h>

// ---------------------------------------------------------------------------
// 4-layer GCN forward (PyG gcn_norm: add self-loops, D^-1/2 A D^-1/2)
// Hidden layers (reassociated): h' = relu((A·h)·W + b), fused gather+GEMM.
//   Intermediates stored as BF16 (RNE): halves the random-gather traffic,
//   which R4-R6 established as a latency*concurrency floor proportional to
//   logical gathered bytes. Accumulation stays f32; W stays f32.
// Last layer (direct order): hw3 = h2@W3 (dense, f32 out), then
//   out = A·hw3 + b3 (f32 gather, 16MB footprint).
// ---------------------------------------------------------------------------

#define F_DIM 128

#define SCAN_T 256
#define SCAN_I 8
#define SCAN_CHUNK (SCAN_T * SCAN_I)   // 2048 items per block

__device__ __forceinline__ unsigned short f2bf_rne(float f) {
    unsigned int u = __float_as_uint(f);
    unsigned int r = (u + 0x7fffu + ((u >> 16) & 1u)) >> 16;
    return (unsigned short)r;
}

__global__ void count_dst_kernel(const int* __restrict__ dst, int* __restrict__ count, int E) {
    int e = blockIdx.x * blockDim.x + threadIdx.x;
    if (e < E) atomicAdd(&count[dst[e]], 1);
}

__global__ void dinv_kernel(const int* __restrict__ count, float* __restrict__ dinv, int n) {
    int i = blockIdx.x * blockDim.x + threadIdx.x;
    if (i < n) dinv[i] = rsqrtf((float)(count[i] + 1));  // +1 self-loop, always > 0
}

// ---- two-level scan of (count[i]+1) ---------------------------------------
__global__ __launch_bounds__(SCAN_T) void scan_partial_kernel(const int* __restrict__ count,
                                                              int* __restrict__ blocksum, int n) {
    int b = blockIdx.x, t = threadIdx.x;
    int base = b * SCAN_CHUNK + t * SCAN_I;
    int s = 0;
#pragma unroll
    for (int j = 0; j < SCAN_I; ++j) {
        int i = base + j;
        if (i < n) s += count[i] + 1;
    }
    __shared__ int red[SCAN_T];
    red[t] = s;
    __syncthreads();
    for (int off = SCAN_T / 2; off > 0; off >>= 1) {
        if (t < off) red[t] += red[t + off];
        __syncthreads();
    }
    if (t == 0) blocksum[b] = red[0];
}

__global__ __launch_bounds__(1024) void scan_sums_kernel(const int* __restrict__ blocksum,
                                                         int* __restrict__ blockoff, int nb) {
    __shared__ int sums[1024];
    int t = threadIdx.x;
    sums[t] = (t < nb) ? blocksum[t] : 0;
    __syncthreads();
    for (int off = 1; off < 1024; off <<= 1) {
        int v = (t >= off) ? sums[t - off] : 0;
        __syncthreads();
        sums[t] += v;
        __syncthreads();
    }
    if (t < nb) blockoff[t] = (t == 0) ? 0 : sums[t - 1];
    if (t == 0) blockoff[nb] = sums[nb - 1];
}

__global__ __launch_bounds__(SCAN_T) void scan_write_kernel(const int* __restrict__ count,
                                                            const int* __restrict__ blockoff,
                                                            int* __restrict__ rowptr,
                                                            int* __restrict__ writepos,
                                                            int n, int nb) {
    int b = blockIdx.x, t = threadIdx.x;
    int base = b * SCAN_CHUNK + t * SCAN_I;
    int c[SCAN_I];
    int s = 0;
#pragma unroll
    for (int j = 0; j < SCAN_I; ++j) {
        int i = base + j;
        c[j] = (i < n) ? count[i] + 1 : 0;
        s += c[j];
    }
    __shared__ int sums[SCAN_T];
    sums[t] = s;
    __syncthreads();
    for (int off = 1; off < SCAN_T; off <<= 1) {
        int v = (t >= off) ? sums[t - off] : 0;
        __syncthreads();
        sums[t] += v;
        __syncthreads();
    }
    int offset = blockoff[b] + ((t == 0) ? 0 : sums[t - 1]);
#pragma unroll
    for (int j = 0; j < SCAN_I; ++j) {
        int i = base + j;
        if (i < n) {
            rowptr[i] = offset;
            writepos[i] = offset;
            offset += c[j];
        }
    }
    if (b == 0 && t == 0) rowptr[n] = blockoff[nb];
}

// ---- CSR fill -------------------------------------------------------------
__global__ void fill_self_kernel(int* __restrict__ writepos, int* __restrict__ col,
                                 float* __restrict__ val, const float* __restrict__ dinv, int n) {
    int i = blockIdx.x * blockDim.x + threadIdx.x;
    if (i < n) {
        int p = atomicAdd(&writepos[i], 1);
        col[p] = i;
        val[p] = dinv[i] * dinv[i];
    }
}

__global__ void fill_edges_kernel(const int* __restrict__ src, const int* __restrict__ dst,
                                  int* __restrict__ writepos, int* __restrict__ col,
                                  float* __restrict__ val, const float* __restrict__ dinv, int E) {
    int e = blockIdx.x * blockDim.x + threadIdx.x;
    if (e < E) {
        int s = src[e], d = dst[e];
        int p = atomicAdd(&writepos[d], 1);
        col[p] = s;
        val[p] = dinv[s] * dinv[d];
    }
}

// ---- f32 -> bf16 conversion (x input), 8 elems/thread ---------------------
__global__ __launch_bounds__(256) void cvt_bf16_kernel(const float* __restrict__ in,
                                                       unsigned short* __restrict__ out,
                                                       long nChunks) {  // nChunks = nElem/8
    long idx = (long)blockIdx.x * 256 + threadIdx.x;
    if (idx >= nChunks) return;
    const float4* in4 = (const float4*)in;
    float4 a = in4[idx * 2];
    float4 b = in4[idx * 2 + 1];
    uint4 o;
    o.x = (unsigned)f2bf_rne(a.x) | ((unsigned)f2bf_rne(a.y) << 16);
    o.y = (unsigned)f2bf_rne(a.z) | ((unsigned)f2bf_rne(a.w) << 16);
    o.z = (unsigned)f2bf_rne(b.x) | ((unsigned)f2bf_rne(b.y) << 16);
    o.w = (unsigned)f2bf_rne(b.z) | ((unsigned)f2bf_rne(b.w) << 16);
    ((uint4*)out)[idx] = o;
}

// unpack-accumulate: acc[0..7] += v * bf16x8(u)
__device__ __forceinline__ void acc8_bf16(float* acc, uint4 u, float v) {
    unsigned w[4] = {u.x, u.y, u.z, u.w};
#pragma unroll
    for (int i = 0; i < 4; ++i) {
        float lo = __uint_as_float(w[i] << 16);
        float hi = __uint_as_float(w[i] & 0xffff0000u);
        acc[2 * i] += v * lo;
        acc[2 * i + 1] += v * hi;
    }
}

// ---- fused hidden layer (bf16 in / bf16 out):
// out[32 nodes] = relu( (A·Hin)[32x128] @ W[128x128] + b )
// block = 256 threads, 32 nodes/block, 8 threads/node
__global__ __launch_bounds__(256, 6) void fused_layer_bf16(const int* __restrict__ rowptr,
                                                           const int* __restrict__ col,
                                                           const float* __restrict__ val,
                                                           const unsigned short* __restrict__ Hin,
                                                           const float* __restrict__ W,
                                                           const float* __restrict__ bias,
                                                           unsigned short* __restrict__ Hout,
                                                           int n) {
    __shared__ float agg[32][132];

    const uint4* H16 = (const uint4*)Hin;   // row = 16 uint4 (128 bf16)
    const float4* W4 = (const float4*)W;

    // ---- phase 1: aggregate 32 rows into LDS, 8 threads/node ----
    // Lane p owns uint4 indices {p, p+8}: 8 lanes x 16B = 128B contiguous
    // per wave instruction per row-half.
    {
        int m = threadIdx.x >> 3;
        int p = threadIdx.x & 7;
        int node = blockIdx.x * 32 + m;
        float acc[16];
#pragma unroll
        for (int q = 0; q < 16; ++q) acc[q] = 0.f;
        if (node < n) {
            int s = rowptr[node], e = rowptr[node + 1];
            int j = s;
            for (; j + 1 < e; j += 2) {
                int c0 = col[j], c1 = col[j + 1];
                float v0 = val[j], v1 = val[j + 1];
                const uint4* r0 = H16 + (size_t)c0 * 16 + p;
                const uint4* r1 = H16 + (size_t)c1 * 16 + p;
                uint4 a0 = r0[0], a1 = r0[8];
                uint4 b0 = r1[0], b1 = r1[8];
                acc8_bf16(acc + 0, a0, v0);
                acc8_bf16(acc + 8, a1, v0);
                acc8_bf16(acc + 0, b0, v1);
                acc8_bf16(acc + 8, b1, v1);
            }
            if (j < e) {
                int c0 = col[j];
                float v0 = val[j];
                const uint4* r0 = H16 + (size_t)c0 * 16 + p;
                uint4 a0 = r0[0], a1 = r0[8];
                acc8_bf16(acc + 0, a0, v0);
                acc8_bf16(acc + 8, a1, v0);
            }
        }
        // features [8p..8p+8) and [64+8p..64+8p+8)
        *(float4*)&agg[m][8 * p] = make_float4(acc[0], acc[1], acc[2], acc[3]);
        *(float4*)&agg[m][8 * p + 4] = make_float4(acc[4], acc[5], acc[6], acc[7]);
        *(float4*)&agg[m][64 + 8 * p] = make_float4(acc[8], acc[9], acc[10], acc[11]);
        *(float4*)&agg[m][64 + 8 * p + 4] = make_float4(acc[12], acc[13], acc[14], acc[15]);
    }
    __syncthreads();

    // ---- phase 2: agg[32][128] @ W[128][128] from L2, register GEMM ----
    constexpr int TXM = 32;
    constexpr int NG = 256 / TXM;      // 8 row groups
    constexpr int ROWS = 32 / NG;      // 4 rows per thread
    int tx = threadIdx.x & (TXM - 1);
    int ty = threadIdx.x / TXM;

    float4 oacc[ROWS];
#pragma unroll
    for (int i = 0; i < ROWS; ++i) oacc[i] = make_float4(0.f, 0.f, 0.f, 0.f);

#pragma unroll 4
    for (int k = 0; k < 128; ++k) {
        float4 b = W4[(size_t)k * 32 + tx];
#pragma unroll
        for (int i = 0; i < ROWS; ++i) {
            float a = agg[i * NG + ty][k];
            oacc[i].x += a * b.x;
            oacc[i].y += a * b.y;
            oacc[i].z += a * b.z;
            oacc[i].w += a * b.w;
        }
    }

    float4 bv = ((const float4*)bias)[tx];
#pragma unroll
    for (int i = 0; i < ROWS; ++i) {
        int node = blockIdx.x * 32 + i * NG + ty;
        if (node < n) {
            float ox = fmaxf(oacc[i].x + bv.x, 0.f);
            float oy = fmaxf(oacc[i].y + bv.y, 0.f);
            float oz = fmaxf(oacc[i].z + bv.z, 0.f);
            float ow = fmaxf(oacc[i].w + bv.w, 0.f);
            ushort4 us;
            us.x = f2bf_rne(ox);
            us.y = f2bf_rne(oy);
            us.z = f2bf_rne(oz);
            us.w = f2bf_rne(ow);
            ((ushort4*)Hout)[(size_t)node * 32 + tx] = us;
        }
    }
}

// ---- gemm40: hw3[N][40] = Hbf16[N][128] @ W[128][40] (f32 out, NO bias) ---
// block 256 threads = 64 nodes x 4 feat-groups of 10
__global__ __launch_bounds__(256) void gemm40_bf16_kernel(const unsigned short* __restrict__ H,
                                                          const float* __restrict__ W,
                                                          float* __restrict__ out, int n) {
    __shared__ float hs[64][129];
    __shared__ float ws[128][40];

    int t = threadIdx.x;
    int rowBase = blockIdx.x * 64;

    for (int i = t; i < 128 * 40; i += 256) ((float*)ws)[i] = W[i];
    {
        const uint4* H16 = (const uint4*)H;   // row = 16 uint4
#pragma unroll
        for (int i = 0; i < 4; ++i) {
            int f = t + 256 * i;               // uint4 index in tile (64*16)
            int m = f >> 4, c8 = f & 15;
            int node = rowBase + m;
            uint4 v = make_uint4(0, 0, 0, 0);
            if (node < n) v = H16[(size_t)node * 16 + c8];
            unsigned w[4] = {v.x, v.y, v.z, v.w};
#pragma unroll
            for (int q = 0; q < 4; ++q) {
                hs[m][c8 * 8 + 2 * q] = __uint_as_float(w[q] << 16);
                hs[m][c8 * 8 + 2 * q + 1] = __uint_as_float(w[q] & 0xffff0000u);
            }
        }
    }
    __syncthreads();

    int m = t & 63;
    int g = t >> 6;
    float acc[10];
#pragma unroll
    for (int j = 0; j < 10; ++j) acc[j] = 0.f;

    for (int k = 0; k < 128; ++k) {
        float a = hs[m][k];
        const float* wrow = &ws[k][g * 10];
#pragma unroll
        for (int j = 0; j < 10; ++j) acc[j] += a * wrow[j];
    }

    int node = rowBase + m;
    if (node < n) {
        float* op = out + (size_t)node * 40 + g * 10;
#pragma unroll
        for (int j = 0; j < 10; ++j) op[j] = acc[j];
    }
}

// ---- gather40: out[dst] = sum val * hw3[src] + b3, 40 feats (f32) ---------
__global__ __launch_bounds__(256, 8) void gather40_kernel(const int* __restrict__ rowptr,
                                                          const int* __restrict__ col,
                                                          const float* __restrict__ val,
                                                          const float* __restrict__ hw3,
                                                          const float* __restrict__ bias,
                                                          float* __restrict__ out, int n) {
    int m = threadIdx.x >> 3;
    int p = threadIdx.x & 7;
    int node = blockIdx.x * 32 + m;
    if (node >= n) return;

    float4 acc0 = make_float4(0.f, 0.f, 0.f, 0.f);
    float4 acc1 = make_float4(0.f, 0.f, 0.f, 0.f);

    int s = rowptr[node], e = rowptr[node + 1];
    int j = s;
    for (; j + 1 < e; j += 2) {
        int c0 = col[j], c1 = col[j + 1];
        float v0 = val[j], v1 = val[j + 1];
        const float4* r0 = (const float4*)(hw3 + (size_t)c0 * 40);
        const float4* r1 = (const float4*)(hw3 + (size_t)c1 * 40);
        float4 a0 = r0[p], a1 = r1[p];
        acc0.x += v0 * a0.x + v1 * a1.x;
        acc0.y += v0 * a0.y + v1 * a1.y;
        acc0.z += v0 * a0.z + v1 * a1.z;
        acc0.w += v0 * a0.w + v1 * a1.w;
        if (p < 2) {
            float4 b0 = r0[8 + p], b1 = r1[8 + p];
            acc1.x += v0 * b0.x + v1 * b1.x;
            acc1.y += v0 * b0.y + v1 * b1.y;
            acc1.z += v0 * b0.z + v1 * b1.z;
            acc1.w += v0 * b0.w + v1 * b1.w;
        }
    }
    if (j < e) {
        int c0 = col[j];
        float v0 = val[j];
        const float4* r0 = (const float4*)(hw3 + (size_t)c0 * 40);
        float4 a0 = r0[p];
        acc0.x += v0 * a0.x;
        acc0.y += v0 * a0.y;
        acc0.z += v0 * a0.z;
        acc0.w += v0 * a0.w;
        if (p < 2) {
            float4 b0 = r0[8 + p];
            acc1.x += v0 * b0.x;
            acc1.y += v0 * b0.y;
            acc1.z += v0 * b0.z;
            acc1.w += v0 * b0.w;
        }
    }

    const float4* bi = (const float4*)bias;
    float4 bv = bi[p];
    float4 o0;
    o0.x = acc0.x + bv.x; o0.y = acc0.y + bv.y;
    o0.z = acc0.z + bv.z; o0.w = acc0.w + bv.w;
    ((float4*)(out + (size_t)node * 40))[p] = o0;
    if (p < 2) {
        float4 bw = bi[8 + p];
        float4 o1;
        o1.x = acc1.x + bw.x; o1.y = acc1.y + bw.y;
        o1.z = acc1.z + bw.z; o1.w = acc1.w + bw.w;
        ((float4*)(out + (size_t)node * 40))[8 + p] = o1;
    }
}

extern "C" void kernel_launch(void* const* d_in, const int* in_sizes, int n_in,
                              void* d_out, int out_size, void* d_ws, size_t ws_size,
                              hipStream_t stream) {
    const float* x = (const float*)d_in[0];
    const int* edge_index = (const int*)d_in[1];
    const float* W0 = (const float*)d_in[2];
    const float* b0 = (const float*)d_in[3];
    const float* W1 = (const float*)d_in[4];
    const float* b1 = (const float*)d_in[5];
    const float* W2 = (const float*)d_in[6];
    const float* b2 = (const float*)d_in[7];
    const float* W3 = (const float*)d_in[8];
    const float* b3 = (const float*)d_in[9];

    const int E = in_sizes[1] / 2;
    const int N = in_sizes[0] / F_DIM;
    const int NNZ = E + N;
    const int NB = (N + SCAN_CHUNK - 1) / SCAN_CHUNK;

    const int* src = edge_index;
    const int* dst = edge_index + E;

    char* ws = (char*)d_ws;
    size_t off = 0;
    auto carve = [&](size_t bytes) -> void* {
        void* p = ws + off;
        off = (off + bytes + 255) & ~(size_t)255;
        return p;
    };
    unsigned short* hbA = (unsigned short*)carve((size_t)N * F_DIM * sizeof(unsigned short));
    unsigned short* hbB = (unsigned short*)carve((size_t)N * F_DIM * sizeof(unsigned short));
    float* hw3 = (float*)carve((size_t)N * 40 * sizeof(float));
    int* count = (int*)carve((size_t)N * sizeof(int));
    float* dinv = (float*)carve((size_t)N * sizeof(float));
    int* rowptr = (int*)carve((size_t)(N + 1) * sizeof(int));
    int* writepos = (int*)carve((size_t)N * sizeof(int));
    int* colbuf = (int*)carve((size_t)NNZ * sizeof(int));
    float* valbuf = (float*)carve((size_t)NNZ * sizeof(float));
    int* blocksum = (int*)carve((size_t)NB * sizeof(int));
    int* blockoff = (int*)carve((size_t)(NB + 1) * sizeof(int));
    (void)ws_size;

    // preprocessing: degree -> dinv -> scan -> CSR fill (+ x -> bf16 overlapped)
    hipMemsetAsync(count, 0, (size_t)N * sizeof(int), stream);
    count_dst_kernel<<<(E + 255) / 256, 256, 0, stream>>>(dst, count, E);
    {
        long nChunks = (long)N * F_DIM / 8;
        cvt_bf16_kernel<<<(int)((nChunks + 255) / 256), 256, 0, stream>>>(x, hbA, nChunks);
    }
    dinv_kernel<<<(N + 255) / 256, 256, 0, stream>>>(count, dinv, N);
    scan_partial_kernel<<<NB, SCAN_T, 0, stream>>>(count, blocksum, N);
    scan_sums_kernel<<<1, 1024, 0, stream>>>(blocksum, blockoff, NB);
    scan_write_kernel<<<NB, SCAN_T, 0, stream>>>(count, blockoff, rowptr, writepos, N, NB);
    fill_self_kernel<<<(N + 255) / 256, 256, 0, stream>>>(writepos, colbuf, valbuf, dinv, N);
    fill_edges_kernel<<<(E + 255) / 256, 256, 0, stream>>>(src, dst, writepos, colbuf, valbuf, dinv, E);

    // 3 fused hidden layers (bf16 storage): hbA -> hbB -> hbA -> hbB
    int nblk32 = (N + 31) / 32;
    fused_layer_bf16<<<nblk32, 256, 0, stream>>>(rowptr, colbuf, valbuf, hbA, W0, b0, hbB, N);
    fused_layer_bf16<<<nblk32, 256, 0, stream>>>(rowptr, colbuf, valbuf, hbB, W1, b1, hbA, N);
    fused_layer_bf16<<<nblk32, 256, 0, stream>>>(rowptr, colbuf, valbuf, hbA, W2, b2, hbB, N);

    // last layer: hw3 = h2 @ W3 (dense, f32), then out = A·hw3 + b3
    gemm40_bf16_kernel<<<(N + 63) / 64, 256, 0, stream>>>(hbB, W3, hw3, N);
    gather40_kernel<<<nblk32, 256, 0, stream>>>(rowptr, colbuf, valbuf, hw3, b3, (float*)d_out, N);
}

// Round 9
// 290.165 us; speedup vs baseline: 1.9459x; 1.2699x over previous
//
#include <hip/hip_runtime.h>
#include <hip/hip_bf16.h>

// ---------------------------------------------------------------------------
// 4-layer GCN forward (PyG gcn_norm: add self-loops, D^-1/2 A D^-1/2)
// Hidden layers (reassociated): h' = relu((A·h)·W + b), fused gather+MFMA.
//   - intermediates h stored bf16 (halves gather traffic; R7-verified)
//   - phase 1: gather 32 node rows, f32 accumulate, pack bf16 into LDS
//   - phase 2: 32x128 @ 128x128 via v_mfma_f32_16x16x32_bf16 (W as bf16,
//     pre-transposed WT[col][k] so B-frags are contiguous 16B loads)
// Last layer: hw3 = h2@W3 dense (f32), then out = A·hw3 + b3 (16MB gather).
// ---------------------------------------------------------------------------

#define F_DIM 128

#define SCAN_T 256
#define SCAN_I 8
#define SCAN_CHUNK (SCAN_T * SCAN_I)   // 2048 items per block

typedef __attribute__((ext_vector_type(8))) short short8;
typedef __attribute__((ext_vector_type(4))) float f32x4;

__device__ __forceinline__ unsigned short f2bf_rne(float f) {
    unsigned int u = __float_as_uint(f);
    unsigned int r = (u + 0x7fffu + ((u >> 16) & 1u)) >> 16;
    return (unsigned short)r;
}

__global__ void count_dst_kernel(const int* __restrict__ dst, int* __restrict__ count, int E) {
    int e = blockIdx.x * blockDim.x + threadIdx.x;
    if (e < E) atomicAdd(&count[dst[e]], 1);
}

__global__ void dinv_kernel(const int* __restrict__ count, float* __restrict__ dinv, int n) {
    int i = blockIdx.x * blockDim.x + threadIdx.x;
    if (i < n) dinv[i] = rsqrtf((float)(count[i] + 1));  // +1 self-loop, always > 0
}

// ---- two-level scan of (count[i]+1) ---------------------------------------
__global__ __launch_bounds__(SCAN_T) void scan_partial_kernel(const int* __restrict__ count,
                                                              int* __restrict__ blocksum, int n) {
    int b = blockIdx.x, t = threadIdx.x;
    int base = b * SCAN_CHUNK + t * SCAN_I;
    int s = 0;
#pragma unroll
    for (int j = 0; j < SCAN_I; ++j) {
        int i = base + j;
        if (i < n) s += count[i] + 1;
    }
    __shared__ int red[SCAN_T];
    red[t] = s;
    __syncthreads();
    for (int off = SCAN_T / 2; off > 0; off >>= 1) {
        if (t < off) red[t] += red[t + off];
        __syncthreads();
    }
    if (t == 0) blocksum[b] = red[0];
}

__global__ __launch_bounds__(1024) void scan_sums_kernel(const int* __restrict__ blocksum,
                                                         int* __restrict__ blockoff, int nb) {
    __shared__ int sums[1024];
    int t = threadIdx.x;
    sums[t] = (t < nb) ? blocksum[t] : 0;
    __syncthreads();
    for (int off = 1; off < 1024; off <<= 1) {
        int v = (t >= off) ? sums[t - off] : 0;
        __syncthreads();
        sums[t] += v;
        __syncthreads();
    }
    if (t < nb) blockoff[t] = (t == 0) ? 0 : sums[t - 1];
    if (t == 0) blockoff[nb] = sums[nb - 1];
}

__global__ __launch_bounds__(SCAN_T) void scan_write_kernel(const int* __restrict__ count,
                                                            const int* __restrict__ blockoff,
                                                            int* __restrict__ rowptr,
                                                            int* __restrict__ writepos,
                                                            int n, int nb) {
    int b = blockIdx.x, t = threadIdx.x;
    int base = b * SCAN_CHUNK + t * SCAN_I;
    int c[SCAN_I];
    int s = 0;
#pragma unroll
    for (int j = 0; j < SCAN_I; ++j) {
        int i = base + j;
        c[j] = (i < n) ? count[i] + 1 : 0;
        s += c[j];
    }
    __shared__ int sums[SCAN_T];
    sums[t] = s;
    __syncthreads();
    for (int off = 1; off < SCAN_T; off <<= 1) {
        int v = (t >= off) ? sums[t - off] : 0;
        __syncthreads();
        sums[t] += v;
        __syncthreads();
    }
    int offset = blockoff[b] + ((t == 0) ? 0 : sums[t - 1]);
#pragma unroll
    for (int j = 0; j < SCAN_I; ++j) {
        int i = base + j;
        if (i < n) {
            rowptr[i] = offset;
            writepos[i] = offset;
            offset += c[j];
        }
    }
    if (b == 0 && t == 0) rowptr[n] = blockoff[nb];
}

// ---- CSR fill -------------------------------------------------------------
__global__ void fill_self_kernel(int* __restrict__ writepos, int* __restrict__ col,
                                 float* __restrict__ val, const float* __restrict__ dinv, int n) {
    int i = blockIdx.x * blockDim.x + threadIdx.x;
    if (i < n) {
        int p = atomicAdd(&writepos[i], 1);
        col[p] = i;
        val[p] = dinv[i] * dinv[i];
    }
}

__global__ void fill_edges_kernel(const int* __restrict__ src, const int* __restrict__ dst,
                                  int* __restrict__ writepos, int* __restrict__ col,
                                  float* __restrict__ val, const float* __restrict__ dinv, int E) {
    int e = blockIdx.x * blockDim.x + threadIdx.x;
    if (e < E) {
        int s = src[e], d = dst[e];
        int p = atomicAdd(&writepos[d], 1);
        col[p] = s;
        val[p] = dinv[s] * dinv[d];
    }
}

// ---- f32 -> bf16 conversion (x input), 8 elems/thread ---------------------
__global__ __launch_bounds__(256) void cvt_bf16_kernel(const float* __restrict__ in,
                                                       unsigned short* __restrict__ out,
                                                       long nChunks) {  // nChunks = nElem/8
    long idx = (long)blockIdx.x * 256 + threadIdx.x;
    if (idx >= nChunks) return;
    const float4* in4 = (const float4*)in;
    float4 a = in4[idx * 2];
    float4 b = in4[idx * 2 + 1];
    uint4 o;
    o.x = (unsigned)f2bf_rne(a.x) | ((unsigned)f2bf_rne(a.y) << 16);
    o.y = (unsigned)f2bf_rne(a.z) | ((unsigned)f2bf_rne(a.w) << 16);
    o.z = (unsigned)f2bf_rne(b.x) | ((unsigned)f2bf_rne(b.y) << 16);
    o.w = (unsigned)f2bf_rne(b.z) | ((unsigned)f2bf_rne(b.w) << 16);
    ((uint4*)out)[idx] = o;
}

// ---- W[128][128] f32 -> WT[c][k] bf16 (transpose + convert) ---------------
__global__ __launch_bounds__(256) void cvt_wt_kernel(const float* __restrict__ W,
                                                     unsigned short* __restrict__ WT) {
    int t = blockIdx.x * 256 + threadIdx.x;   // 0..16383
    int k = t >> 7, c = t & 127;              // read coalesced over c
    WT[(size_t)c * 128 + k] = f2bf_rne(W[(size_t)k * 128 + c]);
}

// unpack-accumulate: acc[0..7] += v * bf16x8(u)
__device__ __forceinline__ void acc8_bf16(float* acc, uint4 u, float v) {
    unsigned w[4] = {u.x, u.y, u.z, u.w};
#pragma unroll
    for (int i = 0; i < 4; ++i) {
        float lo = __uint_as_float(w[i] << 16);
        float hi = __uint_as_float(w[i] & 0xffff0000u);
        acc[2 * i] += v * lo;
        acc[2 * i + 1] += v * hi;
    }
}

// ---- fused hidden layer (bf16 in / bf16 out, MFMA phase 2):
// out[32 nodes] = relu( (A·Hin)[32x128] @ W[128x128] + b )
// block = 256 threads (4 waves), 32 nodes/block, 8 threads/node in phase 1
__global__ __launch_bounds__(256, 8) void fused_layer_mfma(const int* __restrict__ rowptr,
                                                           const int* __restrict__ col,
                                                           const float* __restrict__ val,
                                                           const unsigned short* __restrict__ Hin,
                                                           const unsigned short* __restrict__ WT,
                                                           const float* __restrict__ bias,
                                                           unsigned short* __restrict__ Hout,
                                                           int n) {
    // bf16 agg tile; row pad to 136 ushort (272B) so A-frag ds_read_b128
    // rows (stride 68 words, 68%32=4) spread across bank-quads.
    __shared__ unsigned short aggb[32][136];

    const uint4* H16 = (const uint4*)Hin;   // row = 16 uint4 (128 bf16)

    // ---- phase 1: aggregate 32 rows, f32 accum, pack bf16 into LDS ----
    {
        int m = threadIdx.x >> 3;
        int p = threadIdx.x & 7;
        int node = blockIdx.x * 32 + m;
        float acc[16];
#pragma unroll
        for (int q = 0; q < 16; ++q) acc[q] = 0.f;
        if (node < n) {
            int s = rowptr[node], e = rowptr[node + 1];
            int j = s;
            for (; j + 1 < e; j += 2) {
                int c0 = col[j], c1 = col[j + 1];
                float v0 = val[j], v1 = val[j + 1];
                const uint4* r0 = H16 + (size_t)c0 * 16 + p;
                const uint4* r1 = H16 + (size_t)c1 * 16 + p;
                uint4 a0 = r0[0], a1 = r0[8];
                uint4 b0 = r1[0], b1 = r1[8];
                acc8_bf16(acc + 0, a0, v0);
                acc8_bf16(acc + 8, a1, v0);
                acc8_bf16(acc + 0, b0, v1);
                acc8_bf16(acc + 8, b1, v1);
            }
            if (j < e) {
                int c0 = col[j];
                float v0 = val[j];
                const uint4* r0 = H16 + (size_t)c0 * 16 + p;
                uint4 a0 = r0[0], a1 = r0[8];
                acc8_bf16(acc + 0, a0, v0);
                acc8_bf16(acc + 8, a1, v0);
            }
        }
        // features [8p..8p+8) and [64+8p..64+8p+8), packed bf16
        short8 s0, s1;
#pragma unroll
        for (int q = 0; q < 8; ++q) s0[q] = (short)f2bf_rne(acc[q]);
#pragma unroll
        for (int q = 0; q < 8; ++q) s1[q] = (short)f2bf_rne(acc[8 + q]);
        *(short8*)&aggb[m][8 * p] = s0;
        *(short8*)&aggb[m][64 + 8 * p] = s1;
    }
    __syncthreads();

    // ---- phase 2: agg[32][128] @ W[128][128] via MFMA bf16 ----
    // wave wv owns output cols [32wv, 32wv+32) as 2 n-tiles; 2 m-tiles.
    int lane = threadIdx.x & 63;
    int wv = threadIdx.x >> 6;
    int l15 = lane & 15;
    int lg = lane >> 4;          // k-group: k = kc*32 + lg*8 + i

    f32x4 a00 = {0.f, 0.f, 0.f, 0.f}, a01 = a00, a10 = a00, a11 = a00;

#pragma unroll
    for (int kc = 0; kc < 4; ++kc) {
        int ko = kc * 32 + lg * 8;
        short8 fa0 = *(const short8*)&aggb[l15][ko];
        short8 fa1 = *(const short8*)&aggb[l15 + 16][ko];
        short8 fb0 = *(const short8*)&WT[(size_t)(wv * 32 + l15) * 128 + ko];
        short8 fb1 = *(const short8*)&WT[(size_t)(wv * 32 + 16 + l15) * 128 + ko];
        a00 = __builtin_amdgcn_mfma_f32_16x16x32_bf16(fa0, fb0, a00, 0, 0, 0);
        a01 = __builtin_amdgcn_mfma_f32_16x16x32_bf16(fa0, fb1, a01, 0, 0, 0);
        a10 = __builtin_amdgcn_mfma_f32_16x16x32_bf16(fa1, fb0, a10, 0, 0, 0);
        a11 = __builtin_amdgcn_mfma_f32_16x16x32_bf16(fa1, fb1, a11, 0, 0, 0);
    }

    // ---- epilogue: D col=lane&15, row=(lane>>4)*4+r; bias+relu+bf16 ----
    int base = blockIdx.x * 32;
#pragma unroll
    for (int nt = 0; nt < 2; ++nt) {
        int c = wv * 32 + nt * 16 + l15;
        float bv = bias[c];
#pragma unroll
        for (int mt = 0; mt < 2; ++mt) {
            f32x4 acc = (mt == 0) ? (nt == 0 ? a00 : a01) : (nt == 0 ? a10 : a11);
#pragma unroll
            for (int r = 0; r < 4; ++r) {
                int row = mt * 16 + lg * 4 + r;
                int node = base + row;
                if (node < n) {
                    float o = fmaxf(acc[r] + bv, 0.f);
                    Hout[(size_t)node * 128 + c] = f2bf_rne(o);
                }
            }
        }
    }
}

// ---- gemm40: hw3[N][40] = Hbf16[N][128] @ W[128][40] (f32 out, NO bias) ---
__global__ __launch_bounds__(256) void gemm40_bf16_kernel(const unsigned short* __restrict__ H,
                                                          const float* __restrict__ W,
                                                          float* __restrict__ out, int n) {
    __shared__ float hs[64][129];
    __shared__ float ws[128][40];

    int t = threadIdx.x;
    int rowBase = blockIdx.x * 64;

    for (int i = t; i < 128 * 40; i += 256) ((float*)ws)[i] = W[i];
    {
        const uint4* H16 = (const uint4*)H;
#pragma unroll
        for (int i = 0; i < 4; ++i) {
            int f = t + 256 * i;
            int m = f >> 4, c8 = f & 15;
            int node = rowBase + m;
            uint4 v = make_uint4(0, 0, 0, 0);
            if (node < n) v = H16[(size_t)node * 16 + c8];
            unsigned w[4] = {v.x, v.y, v.z, v.w};
#pragma unroll
            for (int q = 0; q < 4; ++q) {
                hs[m][c8 * 8 + 2 * q] = __uint_as_float(w[q] << 16);
                hs[m][c8 * 8 + 2 * q + 1] = __uint_as_float(w[q] & 0xffff0000u);
            }
        }
    }
    __syncthreads();

    int m = t & 63;
    int g = t >> 6;
    float acc[10];
#pragma unroll
    for (int j = 0; j < 10; ++j) acc[j] = 0.f;

    for (int k = 0; k < 128; ++k) {
        float a = hs[m][k];
        const float* wrow = &ws[k][g * 10];
#pragma unroll
        for (int j = 0; j < 10; ++j) acc[j] += a * wrow[j];
    }

    int node = rowBase + m;
    if (node < n) {
        float* op = out + (size_t)node * 40 + g * 10;
#pragma unroll
        for (int j = 0; j < 10; ++j) op[j] = acc[j];
    }
}

// ---- gather40: out[dst] = sum val * hw3[src] + b3, 40 feats (f32) ---------
__global__ __launch_bounds__(256, 8) void gather40_kernel(const int* __restrict__ rowptr,
                                                          const int* __restrict__ col,
                                                          const float* __restrict__ val,
                                                          const float* __restrict__ hw3,
                                                          const float* __restrict__ bias,
                                                          float* __restrict__ out, int n) {
    int m = threadIdx.x >> 3;
    int p = threadIdx.x & 7;
    int node = blockIdx.x * 32 + m;
    if (node >= n) return;

    float4 acc0 = make_float4(0.f, 0.f, 0.f, 0.f);
    float4 acc1 = make_float4(0.f, 0.f, 0.f, 0.f);

    int s = rowptr[node], e = rowptr[node + 1];
    int j = s;
    for (; j + 1 < e; j += 2) {
        int c0 = col[j], c1 = col[j + 1];
        float v0 = val[j], v1 = val[j + 1];
        const float4* r0 = (const float4*)(hw3 + (size_t)c0 * 40);
        const float4* r1 = (const float4*)(hw3 + (size_t)c1 * 40);
        float4 a0 = r0[p], a1 = r1[p];
        acc0.x += v0 * a0.x + v1 * a1.x;
        acc0.y += v0 * a0.y + v1 * a1.y;
        acc0.z += v0 * a0.z + v1 * a1.z;
        acc0.w += v0 * a0.w + v1 * a1.w;
        if (p < 2) {
            float4 b0 = r0[8 + p], b1 = r1[8 + p];
            acc1.x += v0 * b0.x + v1 * b1.x;
            acc1.y += v0 * b0.y + v1 * b1.y;
            acc1.z += v0 * b0.z + v1 * b1.z;
            acc1.w += v0 * b0.w + v1 * b1.w;
        }
    }
    if (j < e) {
        int c0 = col[j];
        float v0 = val[j];
        const float4* r0 = (const float4*)(hw3 + (size_t)c0 * 40);
        float4 a0 = r0[p];
        acc0.x += v0 * a0.x;
        acc0.y += v0 * a0.y;
        acc0.z += v0 * a0.z;
        acc0.w += v0 * a0.w;
        if (p < 2) {
            float4 b0 = r0[8 + p];
            acc1.x += v0 * b0.x;
            acc1.y += v0 * b0.y;
            acc1.z += v0 * b0.z;
            acc1.w += v0 * b0.w;
        }
    }

    const float4* bi = (const float4*)bias;
    float4 bv = bi[p];
    float4 o0;
    o0.x = acc0.x + bv.x; o0.y = acc0.y + bv.y;
    o0.z = acc0.z + bv.z; o0.w = acc0.w + bv.w;
    ((float4*)(out + (size_t)node * 40))[p] = o0;
    if (p < 2) {
        float4 bw = bi[8 + p];
        float4 o1;
        o1.x = acc1.x + bw.x; o1.y = acc1.y + bw.y;
        o1.z = acc1.z + bw.z; o1.w = acc1.w + bw.w;
        ((float4*)(out + (size_t)node * 40))[8 + p] = o1;
    }
}

extern "C" void kernel_launch(void* const* d_in, const int* in_sizes, int n_in,
                              void* d_out, int out_size, void* d_ws, size_t ws_size,
                              hipStream_t stream) {
    const float* x = (const float*)d_in[0];
    const int* edge_index = (const int*)d_in[1];
    const float* W0 = (const float*)d_in[2];
    const float* b0 = (const float*)d_in[3];
    const float* W1 = (const float*)d_in[4];
    const float* b1 = (const float*)d_in[5];
    const float* W2 = (const float*)d_in[6];
    const float* b2 = (const float*)d_in[7];
    const float* W3 = (const float*)d_in[8];
    const float* b3 = (const float*)d_in[9];

    const int E = in_sizes[1] / 2;
    const int N = in_sizes[0] / F_DIM;
    const int NNZ = E + N;
    const int NB = (N + SCAN_CHUNK - 1) / SCAN_CHUNK;

    const int* src = edge_index;
    const int* dst = edge_index + E;

    char* ws = (char*)d_ws;
    size_t off = 0;
    auto carve = [&](size_t bytes) -> void* {
        void* p = ws + off;
        off = (off + bytes + 255) & ~(size_t)255;
        return p;
    };
    unsigned short* hbA = (unsigned short*)carve((size_t)N * F_DIM * sizeof(unsigned short));
    unsigned short* hbB = (unsigned short*)carve((size_t)N * F_DIM * sizeof(unsigned short));
    float* hw3 = (float*)carve((size_t)N * 40 * sizeof(float));
    unsigned short* WT0 = (unsigned short*)carve(128 * 128 * sizeof(unsigned short));
    unsigned short* WT1 = (unsigned short*)carve(128 * 128 * sizeof(unsigned short));
    unsigned short* WT2 = (unsigned short*)carve(128 * 128 * sizeof(unsigned short));
    int* count = (int*)carve((size_t)N * sizeof(int));
    float* dinv = (float*)carve((size_t)N * sizeof(float));
    int* rowptr = (int*)carve((size_t)(N + 1) * sizeof(int));
    int* writepos = (int*)carve((size_t)N * sizeof(int));
    int* colbuf = (int*)carve((size_t)NNZ * sizeof(int));
    float* valbuf = (float*)carve((size_t)NNZ * sizeof(float));
    int* blocksum = (int*)carve((size_t)NB * sizeof(int));
    int* blockoff = (int*)carve((size_t)(NB + 1) * sizeof(int));
    (void)ws_size;

    // preprocessing: degree -> dinv -> scan -> CSR fill (+ conversions)
    hipMemsetAsync(count, 0, (size_t)N * sizeof(int), stream);
    count_dst_kernel<<<(E + 255) / 256, 256, 0, stream>>>(dst, count, E);
    {
        long nChunks = (long)N * F_DIM / 8;
        cvt_bf16_kernel<<<(int)((nChunks + 255) / 256), 256, 0, stream>>>(x, hbA, nChunks);
    }
    cvt_wt_kernel<<<64, 256, 0, stream>>>(W0, WT0);
    cvt_wt_kernel<<<64, 256, 0, stream>>>(W1, WT1);
    cvt_wt_kernel<<<64, 256, 0, stream>>>(W2, WT2);
    dinv_kernel<<<(N + 255) / 256, 256, 0, stream>>>(count, dinv, N);
    scan_partial_kernel<<<NB, SCAN_T, 0, stream>>>(count, blocksum, N);
    scan_sums_kernel<<<1, 1024, 0, stream>>>(blocksum, blockoff, NB);
    scan_write_kernel<<<NB, SCAN_T, 0, stream>>>(count, blockoff, rowptr, writepos, N, NB);
    fill_self_kernel<<<(N + 255) / 256, 256, 0, stream>>>(writepos, colbuf, valbuf, dinv, N);
    fill_edges_kernel<<<(E + 255) / 256, 256, 0, stream>>>(src, dst, writepos, colbuf, valbuf, dinv, E);

    // 3 fused hidden layers (bf16 storage + MFMA): hbA -> hbB -> hbA -> hbB
    int nblk32 = (N + 31) / 32;
    fused_layer_mfma<<<nblk32, 256, 0, stream>>>(rowptr, colbuf, valbuf, hbA, WT0, b0, hbB, N);
    fused_layer_mfma<<<nblk32, 256, 0, stream>>>(rowptr, colbuf, valbuf, hbB, WT1, b1, hbA, N);
    fused_layer_mfma<<<nblk32, 256, 0, stream>>>(rowptr, colbuf, valbuf, hbA, WT2, b2, hbB, N);

    // last layer: hw3 = h2 @ W3 (dense, f32), then out = A·hw3 + b3
    gemm40_bf16_kernel<<<(N + 63) / 64, 256, 0, stream>>>(hbB, W3, hw3, N);
    gather40_kernel<<<nblk32, 256, 0, stream>>>(rowptr, colbuf, valbuf, hw3, b3, (float*)d_out, N);
}